// Round 10
// baseline (205.338 us; speedup 1.0000x reference)
//
#include <hip/hip_runtime.h>
#include <hip/hip_bf16.h>

typedef __attribute__((ext_vector_type(8))) short short8;
typedef __attribute__((ext_vector_type(4))) short short4v;
typedef __attribute__((ext_vector_type(4))) float f32x4;

#define MFMA16(a,b,c) __builtin_amdgcn_mfma_f32_16x16x32_bf16((a),(b),(c),0,0,0)

constexpr int BHn = 32;     // B*NH
constexpr int Tn  = 2048;
constexpr int Nn  = 512;
constexpr int Dn  = 128;
constexpr int CHn = 64;     // chunk length
constexpr int NCH = Tn / CHn;

static __device__ __forceinline__ unsigned short f2b(float x){
  __hip_bfloat16 h = __float2bfloat16(x);
  return *reinterpret_cast<unsigned short*>(&h);
}

// ---------------- Kernel 1: RoPE(Q) -> bf16 in QUAD-INTERLEAVED layout ----------------
// QRq[bh][t>>2][n][t&3]: shorts addr = (t>>2)*2048 + n*4 + (t&3).
__global__ __launch_bounds__(256) void rope_k(const float* __restrict__ Q,
                                              const float* __restrict__ freqs,
                                              unsigned short* __restrict__ QRq){
  int tq  = blockIdx.x & 511;          // t-quad [0,512)
  int bh0 = (blockIdx.x >> 9) << 3;    // bh group of 8
  int np  = threadIdx.x;               // pair index n in [0,256)
  float f1 = freqs[np], f2 = freqs[np + 256];
  float s1[4], c1[4], s2[4], c2[4];
  #pragma unroll
  for (int i = 0; i < 4; ++i){
    float tf = (float)(tq * 4 + i);
    sincosf(tf * f1, &s1[i], &c1[i]);
    sincosf(tf * f2, &s2[i], &c2[i]);
  }
  for (int b = 0; b < 8; ++b){
    int bh = bh0 + b;
    const float* qp = Q + (size_t)bh * Tn * Nn + (size_t)(tq * 4) * Nn + np;
    short4v o1, o2;
    #pragma unroll
    for (int i = 0; i < 4; ++i){
      float q1 = qp[(size_t)i * Nn], q2 = qp[(size_t)i * Nn + 256];
      o1[i] = (short)f2b(q1 * c1[i] - q2 * s1[i]);   // n = np
      o2[i] = (short)f2b(q2 * c2[i] + q1 * s2[i]);   // n = np+256
    }
    unsigned short* dst = QRq + (size_t)bh * Tn * Nn + (size_t)tq * 2048;
    *reinterpret_cast<short4v*>(dst + np * 4)         = o1;
    *reinterpret_cast<short4v*>(dst + (np + 256) * 4) = o2;
  }
}

// ---------------- LDS fragment loaders (swizzled) ----------------
__device__ __forceinline__ short8 ldfrag(const unsigned short* buf, int rowbase, int k0, int ld, int lane){
  int row = rowbase + (lane & 15);
  int col = (k0 + ((lane >> 4) << 3)) ^ ((row & 7) << 3);
  return *reinterpret_cast<const short8*>(buf + row * ld + col);
}

// ---------------- staging: one QRq uint4 (2 n x 4 dt) -> row-major swizzled Rs ----------
__device__ __forceinline__ void stage_q(unsigned short* Rs, uint4 v, int dt0, int n0){
  unsigned w0 = v.x, w1 = v.y, w2 = v.z, w3 = v.w;
  unsigned o0 = (w0 & 0xffffu) | (w2 << 16);
  unsigned o1 = (w0 >> 16)     | (w2 & 0xffff0000u);
  unsigned o2 = (w1 & 0xffffu) | (w3 << 16);
  unsigned o3 = (w1 >> 16)     | (w3 & 0xffff0000u);
  *reinterpret_cast<unsigned*>(&Rs[(dt0    ) * 512 + (n0 ^ (((dt0    ) & 7) << 3))]) = o0;
  *reinterpret_cast<unsigned*>(&Rs[(dt0 + 1) * 512 + (n0 ^ (((dt0 + 1) & 7) << 3))]) = o1;
  *reinterpret_cast<unsigned*>(&Rs[(dt0 + 2) * 512 + (n0 ^ (((dt0 + 2) & 7) << 3))]) = o2;
  *reinterpret_cast<unsigned*>(&Rs[(dt0 + 3) * 512 + (n0 ^ (((dt0 + 3) & 7) << 3))]) = o3;
}

// ---------------- Kernel 2: chunked linear-attention scan, 8 waves, 2 barriers/chunk ----
// Rebalanced: waves 0-3 = P~ ONLY (3/3/2/2 tile split). Waves 4-7 = state update (quad
// gather) + inter-term oacc for i-tile (w-4) + DEFERRED finish of chunk c-1 (intra MFMA +
// out store) overlapped into Ph1(c). Ps double-buffered to permit the deferral.
__global__ __launch_bounds__(512, 1) void lattn_main(
    const unsigned short* __restrict__ QRq,  // bf16 quad-interleaved (BH,T/4,N,4)
    const float* __restrict__ V,             // (BH,T,D)
    const float* __restrict__ S_prev,        // (BH,N,D)
    const float* __restrict__ gammap,
    float* __restrict__ Out,                 // (BH,T,D)
    float* __restrict__ Sfin)                // (BH,N,D)
{
  __shared__ __align__(16) unsigned short Rs [64 * 512];    // R row-major [dt][n] (64 KB)
  __shared__ __align__(16) unsigned short SbTs[16 * 512];   // bf16(S_start)^T [d][n] (16 KB)
  __shared__ __align__(16) unsigned short VTs[2][16 * 64];  // Vt^T [d][dt] dbuf (4 KB)
  __shared__ __align__(16) unsigned short Ps [2][64 * 64];  // P~ [i][j] dbuf (16 KB)
  __shared__ float gpow[65], gpinv[65];

  const int tid  = threadIdx.x;
  const int w    = tid >> 6;
  const int lane = tid & 63;
  const int bh   = blockIdx.x & 31;   // same bh -> same XCD (blockIdx%8 == bh%8)
  const int dch  = blockIdx.x >> 5;   // 8 d-slices of 16
  const int d0   = dch * 16;
  const float g  = gammap[0];

  const unsigned short* QRbh = QRq + (size_t)bh * Tn * Nn;
  const float* Vbh = V + (size_t)bh * Tn * Dn;

  // ---- prologue ----
  if (tid < 65){
    gpow[tid]  = powf(g,  (float)tid);
    gpinv[tid] = powf(g, -(float)tid);
  }
  #pragma unroll
  for (int i = tid; i < 2 * 64 * 64; i += 512){ Ps[0][i] = 0; }  // strictly-upper tiles stay 0

  f32x4 st[8];  // waves 4-7: state S^T[d][n], 8 n-tiles each
  const int itl = w - 4;              // state wave's out i-tile (0..3)
  if (w >= 4){
    int r0 = itl * 8;
    #pragma unroll
    for (int j = 0; j < 8; ++j){
      int n = (r0 + j) * 16 + (lane & 15);
      const float* sp = S_prev + (size_t)bh * Nn * Dn + (size_t)n * Dn + d0 + ((lane >> 4) << 2);
      st[j] = *reinterpret_cast<const f32x4*>(sp);
    }
  }
  __syncthreads();   // gpow/gpinv ready
  const float g64 = gpow[64];

  // ---- stage chunk 0 ----
  {
    #pragma unroll
    for (int i = 0; i < 8; ++i){
      int p = tid + i * 512;
      int tql = p >> 8, n0 = (p & 255) << 1;
      uint4 v = *reinterpret_cast<const uint4*>(QRbh + (size_t)tql * 2048 + n0 * 4);
      stage_q(Rs, v, tql << 2, n0);
    }
    {
      int dtv = tid >> 3, dp = (tid & 7) << 1;
      const float* vp = Vbh + (size_t)dtv * Dn + d0 + dp;
      float sc = gpinv[dtv];
      VTs[0][ dp      * 64 + (dtv ^ (( dp      & 7) << 3))] = f2b(vp[0] * sc);
      VTs[0][(dp + 1) * 64 + (dtv ^ (((dp + 1) & 7) << 3))] = f2b(vp[1] * sc);
    }
    if (w >= 4){
      int r0 = itl * 8;
      #pragma unroll
      for (int j = 0; j < 8; ++j){
        int n  = (r0 + j) * 16 + (lane & 15);
        int dl = (lane >> 4) << 2;
        #pragma unroll
        for (int r = 0; r < 4; ++r){
          int d = dl + r;
          SbTs[d * 512 + (n ^ ((d & 7) << 3))] = f2b(st[j][r]);
        }
      }
    }
  }
  __syncthreads();   // chunk 0 resident

  f32x4 oacc_p = {0.f, 0.f, 0.f, 0.f};   // state waves: inter term of previous chunk

  for (int c = 0; c < NCH; ++c){
    const int t0 = c * CHn;
    const int q  = c & 1;
    const bool pf = (c + 1 < NCH);
    const unsigned short* Qc = QRbh + (size_t)t0 * Nn;   // this chunk's QRq slice (L2-hot)

    // ---- prefetch chunk c+1 into registers ----
    uint4 rq[8];
    float va0 = 0.f, va1 = 0.f;
    const int dtv_ = tid >> 3;
    if (pf){
      const unsigned short* QRc = QRbh + (size_t)(t0 + CHn) * Nn;
      #pragma unroll
      for (int i = 0; i < 8; ++i){
        int p = tid + i * 512;
        int tql = p >> 8, n0 = (p & 255) << 1;
        rq[i] = *reinterpret_cast<const uint4*>(QRc + (size_t)tql * 2048 + n0 * 4);
      }
      const float* vp = Vbh + (size_t)(t0 + CHn + dtv_) * Dn + d0 + ((tid & 7) << 1);
      va0 = vp[0]; va1 = vp[1];
    }

    // ================= Ph1 =================
    if (w < 4){
      // P~ lower/diag tiles only (round-0 3/3/2/2 split)
      f32x4 p0 = {0.f,0.f,0.f,0.f}, p1 = p0, p2 = p0;
      for (int kb = 0; kb < 16; ++kb){
        int k0 = kb * 32;
        if (w == 0){
          short8 f0 = ldfrag(Rs,  0, k0, 512, lane);
          short8 f1 = ldfrag(Rs, 16, k0, 512, lane);
          p0 = MFMA16(f0, f0, p0);      // (0,0)
          p1 = MFMA16(f1, f0, p1);      // (1,0)
          p2 = MFMA16(f1, f1, p2);      // (1,1)
        } else if (w == 1){
          short8 f0 = ldfrag(Rs,  0, k0, 512, lane);
          short8 f1 = ldfrag(Rs, 16, k0, 512, lane);
          short8 f2 = ldfrag(Rs, 32, k0, 512, lane);
          p0 = MFMA16(f2, f0, p0);      // (2,0)
          p1 = MFMA16(f2, f1, p1);      // (2,1)
          p2 = MFMA16(f2, f2, p2);      // (2,2)
        } else if (w == 2){
          short8 f0 = ldfrag(Rs,  0, k0, 512, lane);
          short8 f1 = ldfrag(Rs, 16, k0, 512, lane);
          short8 f3 = ldfrag(Rs, 48, k0, 512, lane);
          p0 = MFMA16(f3, f0, p0);      // (3,0)
          p1 = MFMA16(f3, f1, p1);      // (3,1)
        } else {
          short8 f2 = ldfrag(Rs, 32, k0, 512, lane);
          short8 f3 = ldfrag(Rs, 48, k0, 512, lane);
          p0 = MFMA16(f3, f2, p0);      // (3,2)
          p1 = MFMA16(f3, f3, p1);      // (3,3)
        }
      }
      // epilogue: P~[i][j] = (j<i) ? gamma^i * acc : 0  -> Ps[q]
      unsigned short* Pq = &Ps[q][0];
      int tI[3], tJ[3], nt;
      if      (w == 0){ tI[0]=0; tJ[0]=0; tI[1]=1; tJ[1]=0; tI[2]=1; tJ[2]=1; nt = 3; }
      else if (w == 1){ tI[0]=2; tJ[0]=0; tI[1]=2; tJ[1]=1; tI[2]=2; tJ[2]=2; nt = 3; }
      else if (w == 2){ tI[0]=3; tJ[0]=0; tI[1]=3; tJ[1]=1; tI[2]=0; tJ[2]=0; nt = 2; }
      else            { tI[0]=3; tJ[0]=2; tI[1]=3; tJ[1]=3; tI[2]=0; tJ[2]=0; nt = 2; }
      f32x4 pacc[3] = {p0, p1, p2};
      for (int z = 0; z < nt; ++z){
        int j  = tJ[z] * 16 + (lane & 15);
        int i0 = tI[z] * 16 + ((lane >> 4) << 2);
        #pragma unroll
        for (int r = 0; r < 4; ++r){
          int i = i0 + r;
          float v = (j < i) ? pacc[z][r] * gpow[i] : 0.f;
          Pq[i * 64 + (j ^ ((i & 7) << 3))] = f2b(v);
        }
      }
    } else {
      // ---- deferred finish of chunk c-1: out = gamma^i * inter + intra ----
      if (c > 0){
        const int qp = q ^ 1;
        float gi = gpow[itl * 16 + (lane & 15)];
        f32x4 o = oacc_p;
        #pragma unroll
        for (int r = 0; r < 4; ++r) o[r] *= gi;
        #pragma unroll
        for (int ks = 0; ks < 2; ++ks){
          short8 av = ldfrag(VTs[qp], 0, ks * 32, 64, lane);
          short8 bp = ldfrag(&Ps[qp][0], itl * 16, ks * 32, 64, lane);
          o = MFMA16(av, bp, o);
        }
        int ti = (t0 - CHn) + itl * 16 + (lane & 15);
        float* op = Out + (size_t)bh * Tn * Dn + (size_t)ti * Dn + d0 + ((lane >> 4) << 2);
        *reinterpret_cast<f32x4*>(op) = o;
      }
      // ---- state update S^T += VTs(A) x QRq-quad-gather(B), then *gamma^64 ----
      int r0 = itl * 8;
      #pragma unroll
      for (int ks = 0; ks < 2; ++ks){
        short8 av = ldfrag(VTs[q], 0, ks * 32, 64, lane);
        #pragma unroll
        for (int j = 0; j < 8; ++j){
          int n   = (r0 + j) * 16 + (lane & 15);
          int dt0 = ks * 32 + ((lane >> 4) << 3);
          const unsigned short* bp = Qc + (size_t)(dt0 >> 2) * 2048 + n * 4;
          short4v lo = *reinterpret_cast<const short4v*>(bp);
          short4v hi = *reinterpret_cast<const short4v*>(bp + 2048);
          short8 bn = __builtin_shufflevector(lo, hi, 0, 1, 2, 3, 4, 5, 6, 7);
          st[j] = MFMA16(av, bn, st[j]);
        }
      }
      #pragma unroll
      for (int j = 0; j < 8; ++j)
        #pragma unroll
        for (int r = 0; r < 4; ++r) st[j][r] *= g64;
      // ---- inter term for this chunk: oacc(i-tile itl) = Sum_k SbT x R ----
      f32x4 oc = {0.f, 0.f, 0.f, 0.f};
      for (int kb = 0; kb < 16; ++kb){
        int k0 = kb * 32;
        short8 fs = ldfrag(SbTs, 0, k0, 512, lane);
        short8 fi = ldfrag(Rs, itl * 16, k0, 512, lane);
        oc = MFMA16(fs, fi, oc);
      }
      oacc_p = oc;
    }
    __syncthreads();

    // ================= Ph2: SbT + staging for c+1 =================
    if (w >= 4){
      int r0 = itl * 8;
      #pragma unroll
      for (int j = 0; j < 8; ++j){
        int n  = (r0 + j) * 16 + (lane & 15);
        int dl = (lane >> 4) << 2;
        #pragma unroll
        for (int r = 0; r < 4; ++r){
          int d = dl + r;
          SbTs[d * 512 + (n ^ ((d & 7) << 3))] = f2b(st[j][r]);
        }
      }
    }
    if (pf){
      #pragma unroll
      for (int i = 0; i < 8; ++i){
        int p = tid + i * 512;
        int tql = p >> 8, n0 = (p & 255) << 1;
        stage_q(Rs, rq[i], tql << 2, n0);
      }
      int dp = (tid & 7) << 1;
      float sc = gpinv[dtv_];
      VTs[q ^ 1][ dp      * 64 + (dtv_ ^ (( dp      & 7) << 3))] = f2b(va0 * sc);
      VTs[q ^ 1][(dp + 1) * 64 + (dtv_ ^ (((dp + 1) & 7) << 3))] = f2b(va1 * sc);
    }
    __syncthreads();
  }

  // ---- tail: finish last chunk + final state ----
  if (w >= 4){
    const int qp = (NCH - 1) & 1;
    float gi = gpow[itl * 16 + (lane & 15)];
    f32x4 o = oacc_p;
    #pragma unroll
    for (int r = 0; r < 4; ++r) o[r] *= gi;
    #pragma unroll
    for (int ks = 0; ks < 2; ++ks){
      short8 av = ldfrag(VTs[qp], 0, ks * 32, 64, lane);
      short8 bp = ldfrag(&Ps[qp][0], itl * 16, ks * 32, 64, lane);
      o = MFMA16(av, bp, o);
    }
    int ti = (NCH - 1) * CHn + itl * 16 + (lane & 15);
    float* op = Out + (size_t)bh * Tn * Dn + (size_t)ti * Dn + d0 + ((lane >> 4) << 2);
    *reinterpret_cast<f32x4*>(op) = o;

    int r0 = itl * 8;
    #pragma unroll
    for (int j = 0; j < 8; ++j){
      int n = (r0 + j) * 16 + (lane & 15);
      float* sp = Sfin + (size_t)bh * Nn * Dn + (size_t)n * Dn + d0 + ((lane >> 4) << 2);
      *reinterpret_cast<f32x4*>(sp) = st[j];
    }
  }
}

extern "C" void kernel_launch(void* const* d_in, const int* in_sizes, int n_in,
                              void* d_out, int out_size, void* d_ws, size_t ws_size,
                              hipStream_t stream){
  const float* Q      = (const float*)d_in[0];
  const float* V      = (const float*)d_in[1];
  const float* S_prev = (const float*)d_in[2];
  const float* freqs  = (const float*)d_in[3];
  const float* gamma  = (const float*)d_in[4];
  float* Out  = (float*)d_out;
  float* Sfin = Out + (size_t)BHn * Tn * Dn;
  unsigned short* QRq = (unsigned short*)d_ws;   // 64 MB bf16 scratch (quad-interleaved)

  rope_k<<<2048, 256, 0, stream>>>(Q, freqs, QRq);
  lattn_main<<<256, 512, 0, stream>>>(QRq, V, S_prev, gamma, Out, Sfin);
}